// Round 4
// baseline (189.226 us; speedup 1.0000x reference)
//
#include <hip/hip_runtime.h>
#include <hip/hip_bf16.h>

typedef unsigned short u16;
typedef unsigned int u32;
typedef __attribute__((ext_vector_type(8))) short short8;
typedef __attribute__((ext_vector_type(4))) short short4_t;
typedef __attribute__((ext_vector_type(4))) float f32x4;

#define L_SEQ 4096
#define NCH 64
#define NBATCH 4
#define NW 8                    // waves per block = KV splits
#define KVSPAN (L_SEQ / NW)     // 512 j per wave

__device__ inline u16 f2bf(float f) {
    union { float f; u32 u; } v; v.f = f;
    u32 r = v.u + 0x7fffu + ((v.u >> 16) & 1u);   // round-to-nearest-even
    return (u16)(r >> 16);
}

// hardware packed f32->bf16 (RNE); low16 = a, high16 = b
__device__ inline u32 cvtpk(float a, float b) {
    u32 r;
    asm("v_cvt_pk_bf16_f32 %0, %1, %2" : "=v"(r) : "v"(a), "v"(b));
    return r;
}

// ---------------- Kernel 1: QKV projection (3x 64x64 channel GEMM) ----------------
// Qt[n][i][c] (bf16), Kt[n][j][c] (bf16), V[n][c][j] (bf16)
__global__ __launch_bounds__(256) void qkv_kernel(
    const float* __restrict__ x,
    const float* __restrict__ wb, const float* __restrict__ bb,
    const float* __restrict__ wc, const float* __restrict__ bc,
    const float* __restrict__ wd, const float* __restrict__ bd,
    u16* __restrict__ Qt, u16* __restrict__ Kt, u16* __restrict__ V)
{
    __shared__ float xs[64][64];       // x tile: [c][px]
    __shared__ float wl[3][64][65];    // padded weights: [mat][o][c]

    const int nb  = blockIdx.y;
    const int i0  = blockIdx.x * 64;
    const int tid = threadIdx.x;

    const float* xbase = x + (size_t)nb * NCH * L_SEQ + i0;
    #pragma unroll
    for (int rep = 0; rep < 16; ++rep) {
        int idx = rep * 256 + tid;
        int c = idx >> 6, px = idx & 63;
        xs[c][px] = xbase[(size_t)c * L_SEQ + px];
    }
    const float* wsrc[3] = { wb, wc, wd };
    for (int m = 0; m < 3; ++m) {
        #pragma unroll
        for (int rep = 0; rep < 16; ++rep) {
            int idx = rep * 256 + tid;
            wl[m][idx >> 6][idx & 63] = wsrc[m][idx];
        }
    }
    __syncthreads();

    const int co  = tid & 63;     // output channel
    const int pg  = tid >> 6;     // pixel group 0..3
    const int px0 = pg * 16;

    float accB[16], accC[16], accD[16];
    const float biasB = bb[co], biasC = bc[co], biasD = bd[co];
    #pragma unroll
    for (int p = 0; p < 16; ++p) { accB[p] = biasB; accC[p] = biasC; accD[p] = biasD; }

    for (int c = 0; c < 64; ++c) {
        const float wbv = wl[0][co][c];
        const float wcv = wl[1][co][c];
        const float wdv = wl[2][co][c];
        #pragma unroll
        for (int p = 0; p < 16; ++p) {
            const float xv = xs[c][px0 + p];
            accB[p] += wbv * xv;
            accC[p] += wcv * xv;
            accD[p] += wdv * xv;
        }
    }

    #pragma unroll
    for (int p = 0; p < 16; ++p) {
        const int i = i0 + px0 + p;
        Kt[((size_t)(nb * L_SEQ + i)) * NCH + co] = f2bf(accB[p]);  // keys    = xb
        Qt[((size_t)(nb * L_SEQ + i)) * NCH + co] = f2bf(accC[p]);  // queries = xc
        V [((size_t)(nb * NCH + co)) * L_SEQ + i] = f2bf(accD[p]);  // values  = xd
    }
}

// ---------------- Kernel 2: flash attention, split-KV, swapped QK^T ----------------
// Block = 8 waves, one q-tile of 16 rows. Wave w covers j in [w*512, w*512+512).
// S^T = mfma(K, Q): lane holds S[i = lane&15][16 j's] -> softmax mostly in-register
// (2 shfl_xor per reduce). P packed to bf16 via v_cvt_pk; PV contraction uses the
// k->j mapping sigma(8*hi+e) = (e<4 ? 4*hi+e : 16+4*hi+e-4) so each lane's own
// packed P is its B-fragment (zero cross-lane exchange, zero LDS in the loop).
__global__ __launch_bounds__(512, 4) void attn_kernel(
    const u16* __restrict__ Qt, const u16* __restrict__ Kt,
    const u16* __restrict__ V,  const float* __restrict__ x,
    const float* __restrict__ alphap, float* __restrict__ out)
{
    __shared__ float smem[NW][16 * 65];   // per-wave partial O [i][c], pad 65
    __shared__ float mlbuf[NW][16][2];

    const int nb   = blockIdx.y;
    const int i0   = blockIdx.x * 16;
    const int tid  = threadIdx.x;
    const int w    = tid >> 6;
    const int lane = tid & 63;
    const int lo   = lane & 15;
    const int hi   = lane >> 4;

    // Q fragments (B operand): col=i=lo, k=c=hi*8+e
    short8 qf0, qf1;
    {
        const u16* qrow = Qt + ((size_t)(nb * L_SEQ + i0 + lo)) * NCH + hi * 8;
        qf0 = *(const short8*)(qrow);
        qf1 = *(const short8*)(qrow + 32);
    }

    const f32x4 zero = { 0.f, 0.f, 0.f, 0.f };
    f32x4 acc_o[4];   // O^T[c][i]: lane holds i=lo, c = ct*16 + hi*4 + r
    #pragma unroll
    for (int ct = 0; ct < 4; ++ct) acc_o[ct] = zero;
    float m_ = -3.0e38f, l_ = 0.f;

    const u16* KtB = Kt + (size_t)nb * L_SEQ * NCH;
    const u16* VB  = V  + (size_t)nb * NCH * L_SEQ;

    union PF { u32 u[4]; short8 s; };
    union VF { short4_t h[2]; short8 s; };

    #pragma unroll 1
    for (int t = 0; t < KVSPAN / 64; ++t) {
        const int j0 = w * KVSPAN + t * 64;

        // ---- S^T = K Q^T (64j x 16i): lane holds s[jt][r] = S[i=lo][j0+jt*16+hi*4+r]
        f32x4 s[4];
        #pragma unroll
        for (int jt = 0; jt < 4; ++jt) {
            const u16* krow = KtB + ((size_t)(j0 + jt * 16 + lo)) * NCH + hi * 8;
            short8 k0 = *(const short8*)(krow);
            short8 k1 = *(const short8*)(krow + 32);
            f32x4 a = zero;
            a = __builtin_amdgcn_mfma_f32_16x16x32_bf16(k0, qf0, a, 0, 0, 0);
            a = __builtin_amdgcn_mfma_f32_16x16x32_bf16(k1, qf1, a, 0, 0, 0);
            s[jt] = a;
        }

        // ---- online softmax over the 16 in-register j's + 2 shfl (lanes lo,lo+16,+32,+48 share i)
        float mx01 = fmaxf(fmaxf(fmaxf(s[0][0], s[0][1]), fmaxf(s[0][2], s[0][3])),
                           fmaxf(fmaxf(s[1][0], s[1][1]), fmaxf(s[1][2], s[1][3])));
        float mx23 = fmaxf(fmaxf(fmaxf(s[2][0], s[2][1]), fmaxf(s[2][2], s[2][3])),
                           fmaxf(fmaxf(s[3][0], s[3][1]), fmaxf(s[3][2], s[3][3])));
        float rm = fmaxf(mx01, mx23);
        rm = fmaxf(rm, __shfl_xor(rm, 16, 64));
        rm = fmaxf(rm, __shfl_xor(rm, 32, 64));

        const float mn  = fmaxf(m_, rm);
        const float scl = __expf(m_ - mn);

        float p[4][4];
        float rs = 0.f;
        #pragma unroll
        for (int jt = 0; jt < 4; ++jt) {
            #pragma unroll
            for (int r = 0; r < 4; ++r) {
                p[jt][r] = __expf(s[jt][r] - mn);
                rs += p[jt][r];
            }
        }
        rs += __shfl_xor(rs, 16, 64);
        rs += __shfl_xor(rs, 32, 64);
        l_ = l_ * scl + rs;
        m_ = mn;

        // ---- pack P to bf16 B-fragments (lane-local, no exchange)
        PF pf0, pf1;
        pf0.u[0] = cvtpk(p[0][0], p[0][1]);   // e0,e1: j=4hi+0,1
        pf0.u[1] = cvtpk(p[0][2], p[0][3]);   // e2,e3: j=4hi+2,3
        pf0.u[2] = cvtpk(p[1][0], p[1][1]);   // e4,e5: j=16+4hi+0,1
        pf0.u[3] = cvtpk(p[1][2], p[1][3]);   // e6,e7: j=16+4hi+2,3
        pf1.u[0] = cvtpk(p[2][0], p[2][1]);   // j=32+4hi+0,1
        pf1.u[1] = cvtpk(p[2][2], p[2][3]);
        pf1.u[2] = cvtpk(p[3][0], p[3][1]);   // j=48+4hi+0,1
        pf1.u[3] = cvtpk(p[3][2], p[3][3]);

        // ---- rescale O by scalar scl
        #pragma unroll
        for (int ct = 0; ct < 4; ++ct)
            #pragma unroll
            for (int r = 0; r < 4; ++r)
                acc_o[ct][r] *= scl;

        // ---- O^T += V^T P^T; A-frag: V[c=ct*16+lo][j0 + sigma], per-mfma two short4 loads
        #pragma unroll
        for (int ct = 0; ct < 4; ++ct) {
            const u16* vrow = VB + ((size_t)(ct * 16 + lo)) * L_SEQ + j0;
            VF v0, v1;
            v0.h[0] = *(const short4_t*)(vrow +      4 * hi);   // e0..3: j=4hi+0..3
            v0.h[1] = *(const short4_t*)(vrow + 16 + 4 * hi);   // e4..7: j=16+4hi+0..3
            v1.h[0] = *(const short4_t*)(vrow + 32 + 4 * hi);
            v1.h[1] = *(const short4_t*)(vrow + 48 + 4 * hi);
            acc_o[ct] = __builtin_amdgcn_mfma_f32_16x16x32_bf16(v0.s, pf0.s, acc_o[ct], 0, 0, 0);
            acc_o[ct] = __builtin_amdgcn_mfma_f32_16x16x32_bf16(v1.s, pf1.s, acc_o[ct], 0, 0, 0);
        }
    }

    // ---- write per-wave partial state to LDS: smem[w][i][c], i=lo, c=ct*16+hi*4+r
    #pragma unroll
    for (int ct = 0; ct < 4; ++ct)
        #pragma unroll
        for (int r = 0; r < 4; ++r)
            smem[w][lo * 65 + ct * 16 + hi * 4 + r] = acc_o[ct][r];
    if (hi == 0) {
        mlbuf[w][lo][0] = m_;
        mlbuf[w][lo][1] = l_;
    }
    __syncthreads();

    // ---- combine 8 partials + epilogue ----
    // thread -> (q = tid&15, c0 = (tid>>4)*2): covers 16 q x 64 c
    const int q  = tid & 15;
    const int c0 = (tid >> 4) * 2;

    float gm = -3.0e38f;
    #pragma unroll
    for (int s2 = 0; s2 < NW; ++s2) gm = fmaxf(gm, mlbuf[s2][q][0]);

    float Ls = 0.f, O0 = 0.f, O1 = 0.f;
    #pragma unroll
    for (int s2 = 0; s2 < NW; ++s2) {
        const float cf = __expf(mlbuf[s2][q][0] - gm);
        Ls += mlbuf[s2][q][1] * cf;
        O0 += smem[s2][q * 65 + c0]     * cf;
        O1 += smem[s2][q * 65 + c0 + 1] * cf;
    }
    const float rl    = __builtin_amdgcn_rcpf(Ls);
    const float alpha = alphap[0];

    const size_t base0 = ((size_t)(nb * NCH + c0)) * L_SEQ + i0 + q;
    out[base0]         = alpha * O0 * rl + x[base0];
    out[base0 + L_SEQ] = alpha * O1 * rl + x[base0 + L_SEQ];
}

extern "C" void kernel_launch(void* const* d_in, const int* in_sizes, int n_in,
                              void* d_out, int out_size, void* d_ws, size_t ws_size,
                              hipStream_t stream) {
    const float* x     = (const float*)d_in[0];
    const float* wb    = (const float*)d_in[1];
    const float* bb    = (const float*)d_in[2];
    const float* wc    = (const float*)d_in[3];
    const float* bc    = (const float*)d_in[4];
    const float* wd    = (const float*)d_in[5];
    const float* bd    = (const float*)d_in[6];
    const float* alpha = (const float*)d_in[7];

    const size_t elems = (size_t)NBATCH * L_SEQ * NCH;  // 1,048,576
    u16* Qt = (u16*)d_ws;
    u16* Kt = Qt + elems;
    u16* V  = Kt + elems;

    qkv_kernel<<<dim3(L_SEQ / 64, NBATCH), 256, 0, stream>>>(
        x, wb, bb, wc, bc, wd, bd, Qt, Kt, V);
    attn_kernel<<<dim3(L_SEQ / 16, NBATCH), 512, 0, stream>>>(
        Qt, Kt, V, x, alpha, (float*)d_out);
}

// Round 5
// 83.769 us; speedup vs baseline: 2.2589x; 2.2589x over previous
//
#include <hip/hip_runtime.h>
#include <hip/hip_bf16.h>

typedef unsigned short u16;
typedef unsigned int u32;
typedef __attribute__((ext_vector_type(8))) short short8;
typedef __attribute__((ext_vector_type(4))) float f32x4;

#define L_SEQ 4096
#define NCH 64
#define NBATCH 4
#define NW 8                    // waves per block = KV splits
#define KVSPAN (L_SEQ / NW)     // 512 j per wave
#define QB 32                   // q-rows per block (shared by all waves)

__device__ inline u16 f2bf(float f) {
    union { float f; u32 u; } v; v.f = f;
    u32 r = v.u + 0x7fffu + ((v.u >> 16) & 1u);   // round-to-nearest-even
    return (u16)(r >> 16);
}

// ---------------- Kernel 1: QKV projection (3x 64x64 channel GEMM) ----------------
// Qt[n][i][c] (bf16), Kt[n][j][c] (bf16), V[n][c][j] (bf16)
__global__ __launch_bounds__(256) void qkv_kernel(
    const float* __restrict__ x,
    const float* __restrict__ wb, const float* __restrict__ bb,
    const float* __restrict__ wc, const float* __restrict__ bc,
    const float* __restrict__ wd, const float* __restrict__ bd,
    u16* __restrict__ Qt, u16* __restrict__ Kt, u16* __restrict__ V)
{
    __shared__ float xs[64][64];       // x tile: [c][px]
    __shared__ float wl[3][64][65];    // padded weights: [mat][o][c]

    const int nb  = blockIdx.y;
    const int i0  = blockIdx.x * 64;
    const int tid = threadIdx.x;

    const float* xbase = x + (size_t)nb * NCH * L_SEQ + i0;
    #pragma unroll
    for (int rep = 0; rep < 16; ++rep) {
        int idx = rep * 256 + tid;
        int c = idx >> 6, px = idx & 63;
        xs[c][px] = xbase[(size_t)c * L_SEQ + px];
    }
    const float* wsrc[3] = { wb, wc, wd };
    for (int m = 0; m < 3; ++m) {
        #pragma unroll
        for (int rep = 0; rep < 16; ++rep) {
            int idx = rep * 256 + tid;
            wl[m][idx >> 6][idx & 63] = wsrc[m][idx];
        }
    }
    __syncthreads();

    const int co  = tid & 63;     // output channel
    const int pg  = tid >> 6;     // pixel group 0..3
    const int px0 = pg * 16;

    float accB[16], accC[16], accD[16];
    const float biasB = bb[co], biasC = bc[co], biasD = bd[co];
    #pragma unroll
    for (int p = 0; p < 16; ++p) { accB[p] = biasB; accC[p] = biasC; accD[p] = biasD; }

    for (int c = 0; c < 64; ++c) {
        const float wbv = wl[0][co][c];
        const float wcv = wl[1][co][c];
        const float wdv = wl[2][co][c];
        #pragma unroll
        for (int p = 0; p < 16; ++p) {
            const float xv = xs[c][px0 + p];
            accB[p] += wbv * xv;
            accC[p] += wcv * xv;
            accD[p] += wdv * xv;
        }
    }

    #pragma unroll
    for (int p = 0; p < 16; ++p) {
        const int i = i0 + px0 + p;
        Kt[((size_t)(nb * L_SEQ + i)) * NCH + co] = f2bf(accB[p]);  // keys    = xb
        Qt[((size_t)(nb * L_SEQ + i)) * NCH + co] = f2bf(accC[p]);  // queries = xc
        V [((size_t)(nb * NCH + co)) * L_SEQ + i] = f2bf(accD[p]);  // values  = xd
    }
}

// ---------------- Kernel 2: flash attention, split-KV, 32 q-rows/wave ----------------
// Block = 8 waves sharing one 32-row q-tile. Wave w covers j in [w*512, (w+1)*512).
// R2 structure (known-good); q-tile doubled 16->32 so K/V load instructions and L2
// bytes halve at constant MFMA/VALU totals (loads are q-independent).
__global__ __launch_bounds__(512, 4) void attn_kernel(
    const u16* __restrict__ Qt, const u16* __restrict__ Kt,
    const u16* __restrict__ V,  const float* __restrict__ x,
    const float* __restrict__ alphap, float* __restrict__ out)
{
    // Per-wave region: 32*65 floats (8320 B). During the KV loop the first
    // 4608 B are the wave-private P-transpose buffer (u16[32][72]); after the
    // loop the region holds the fp32 partial O[32][65] (padded).
    __shared__ float smem[NW][QB * 65];
    __shared__ float mlbuf[NW][QB][2];

    const int nb   = blockIdx.y;
    const int i0   = blockIdx.x * QB;
    const int tid  = threadIdx.x;
    const int w    = tid >> 6;
    const int lane = tid & 63;
    const int lo   = lane & 15;
    const int hi   = lane >> 4;

    u16* pbuf = (u16*)(&smem[w][0]);   // [32][72] u16, stride 144 B

    // Q fragments: A[row=lo][k=c], qt selects 16-row half of the 32-row q-tile
    short8 qf[2][2];
    #pragma unroll
    for (int qt = 0; qt < 2; ++qt) {
        const u16* qrow = Qt + ((size_t)(nb * L_SEQ + i0 + qt * 16 + lo)) * NCH + hi * 8;
        qf[qt][0] = *(const short8*)(qrow);
        qf[qt][1] = *(const short8*)(qrow + 32);
    }

    const f32x4 zero = { 0.f, 0.f, 0.f, 0.f };
    f32x4 acc_o[2][4];                 // [qt][ct]; rows q=qt*16+hi*4+r, col c=ct*16+lo
    #pragma unroll
    for (int qt = 0; qt < 2; ++qt)
        #pragma unroll
        for (int ct = 0; ct < 4; ++ct) acc_o[qt][ct] = zero;
    float m_[2][4], l_[2][4];
    #pragma unroll
    for (int qt = 0; qt < 2; ++qt)
        #pragma unroll
        for (int r = 0; r < 4; ++r) { m_[qt][r] = -3.0e38f; l_[qt][r] = 0.f; }

    const u16* KtB = Kt + (size_t)nb * L_SEQ * NCH;
    const u16* VB  = V  + (size_t)nb * NCH * L_SEQ;

    #pragma unroll 1
    for (int t = 0; t < KVSPAN / 64; ++t) {
        const int j0 = w * KVSPAN + t * 64;

        // ---- S = Q K^T (32 x 64); K loads shared across both q-halves ----
        f32x4 s[2][4];
        #pragma unroll
        for (int jt = 0; jt < 4; ++jt) {
            const u16* krow = KtB + ((size_t)(j0 + jt * 16 + lo)) * NCH + hi * 8;
            short8 k0 = *(const short8*)(krow);
            short8 k1 = *(const short8*)(krow + 32);
            #pragma unroll
            for (int qt = 0; qt < 2; ++qt) {
                f32x4 a = zero;
                a = __builtin_amdgcn_mfma_f32_16x16x32_bf16(qf[qt][0], k0, a, 0, 0, 0);
                a = __builtin_amdgcn_mfma_f32_16x16x32_bf16(qf[qt][1], k1, a, 0, 0, 0);
                s[qt][jt] = a;
            }
        }

        // ---- online softmax; row q = qt*16+hi*4+r, col j = jt*16+lo ----
        float scl[2][4];
        #pragma unroll
        for (int qt = 0; qt < 2; ++qt) {
            #pragma unroll
            for (int r = 0; r < 4; ++r) {
                float rm = fmaxf(fmaxf(s[qt][0][r], s[qt][1][r]),
                                 fmaxf(s[qt][2][r], s[qt][3][r]));
                #pragma unroll
                for (int msk = 1; msk < 16; msk <<= 1)
                    rm = fmaxf(rm, __shfl_xor(rm, msk, 64));
                const float mn = fmaxf(m_[qt][r], rm);
                scl[qt][r] = __expf(m_[qt][r] - mn);
                float rs = 0.f;
                float pv[4];
                #pragma unroll
                for (int jt = 0; jt < 4; ++jt) {
                    pv[jt] = __expf(s[qt][jt][r] - mn);
                    rs += pv[jt];
                }
                #pragma unroll
                for (int msk = 1; msk < 16; msk <<= 1)
                    rs += __shfl_xor(rs, msk, 64);
                l_[qt][r] = l_[qt][r] * scl[qt][r] + rs;
                m_[qt][r] = mn;
                // ---- P -> per-wave LDS (transpose to A-fragment layout) ----
                #pragma unroll
                for (int jt = 0; jt < 4; ++jt)
                    pbuf[(qt * 16 + hi * 4 + r) * 72 + jt * 16 + lo] = f2bf(pv[jt]);
            }
        }

        // wave-private buffer: drain this wave's LDS ops only (in-order DS pipe
        // per wave); no block barrier. sched_barrier per rule 18.
        asm volatile("s_waitcnt lgkmcnt(0)" ::: "memory");
        __builtin_amdgcn_sched_barrier(0);

        short8 pf[2][2];
        #pragma unroll
        for (int qt = 0; qt < 2; ++qt) {
            pf[qt][0] = *(const short8*)&pbuf[(qt * 16 + lo) * 72 + hi * 8];
            pf[qt][1] = *(const short8*)&pbuf[(qt * 16 + lo) * 72 + 32 + hi * 8];
        }

        // ---- rescale O ----
        #pragma unroll
        for (int qt = 0; qt < 2; ++qt)
            #pragma unroll
            for (int ct = 0; ct < 4; ++ct)
                #pragma unroll
                for (int r = 0; r < 4; ++r)
                    acc_o[qt][ct][r] *= scl[qt][r];

        // ---- O += P V^T; V loads shared across both q-halves ----
        #pragma unroll
        for (int ct = 0; ct < 4; ++ct) {
            const u16* vrow = VB + ((size_t)(ct * 16 + lo)) * L_SEQ + j0 + hi * 8;
            short8 v0 = *(const short8*)(vrow);
            short8 v1 = *(const short8*)(vrow + 32);
            #pragma unroll
            for (int qt = 0; qt < 2; ++qt) {
                acc_o[qt][ct] = __builtin_amdgcn_mfma_f32_16x16x32_bf16(pf[qt][0], v0, acc_o[qt][ct], 0, 0, 0);
                acc_o[qt][ct] = __builtin_amdgcn_mfma_f32_16x16x32_bf16(pf[qt][1], v1, acc_o[qt][ct], 0, 0, 0);
            }
        }
    }

    // ---- write per-wave partial state to LDS ----
    #pragma unroll
    for (int qt = 0; qt < 2; ++qt)
        #pragma unroll
        for (int ct = 0; ct < 4; ++ct)
            #pragma unroll
            for (int r = 0; r < 4; ++r)
                smem[w][(qt * 16 + hi * 4 + r) * 65 + ct * 16 + lo] = acc_o[qt][ct][r];
    if (lo == 0) {
        #pragma unroll
        for (int qt = 0; qt < 2; ++qt)
            #pragma unroll
            for (int r = 0; r < 4; ++r) {
                mlbuf[w][qt * 16 + hi * 4 + r][0] = m_[qt][r];
                mlbuf[w][qt * 16 + hi * 4 + r][1] = l_[qt][r];
            }
    }
    __syncthreads();

    // ---- combine 8 partials + epilogue ----
    // thread -> (q = tid&31, c0 = (tid>>5)*4): covers 32 q x 64 c
    const int q  = tid & 31;
    const int c0 = (tid >> 5) * 4;

    float gm = -3.0e38f;
    #pragma unroll
    for (int s2 = 0; s2 < NW; ++s2) gm = fmaxf(gm, mlbuf[s2][q][0]);

    float Ls = 0.f, O[4] = { 0.f, 0.f, 0.f, 0.f };
    #pragma unroll
    for (int s2 = 0; s2 < NW; ++s2) {
        const float cf = __expf(mlbuf[s2][q][0] - gm);
        Ls += mlbuf[s2][q][1] * cf;
        #pragma unroll
        for (int k = 0; k < 4; ++k)
            O[k] += smem[s2][q * 65 + c0 + k] * cf;
    }
    const float rl    = __builtin_amdgcn_rcpf(Ls);
    const float alpha = alphap[0];

    #pragma unroll
    for (int k = 0; k < 4; ++k) {
        const size_t idx = ((size_t)(nb * NCH + c0 + k)) * L_SEQ + i0 + q;
        out[idx] = alpha * O[k] * rl + x[idx];
    }
}

extern "C" void kernel_launch(void* const* d_in, const int* in_sizes, int n_in,
                              void* d_out, int out_size, void* d_ws, size_t ws_size,
                              hipStream_t stream) {
    const float* x     = (const float*)d_in[0];
    const float* wb    = (const float*)d_in[1];
    const float* bb    = (const float*)d_in[2];
    const float* wc    = (const float*)d_in[3];
    const float* bc    = (const float*)d_in[4];
    const float* wd    = (const float*)d_in[5];
    const float* bd    = (const float*)d_in[6];
    const float* alpha = (const float*)d_in[7];

    const size_t elems = (size_t)NBATCH * L_SEQ * NCH;  // 1,048,576
    u16* Qt = (u16*)d_ws;
    u16* Kt = Qt + elems;
    u16* V  = Kt + elems;

    qkv_kernel<<<dim3(L_SEQ / 64, NBATCH), 256, 0, stream>>>(
        x, wb, bb, wc, bc, wd, bd, Qt, Kt, V);
    attn_kernel<<<dim3(L_SEQ / QB, NBATCH), 512, 0, stream>>>(
        Qt, Kt, V, x, alpha, (float*)d_out);
}

// Round 6
// 64.951 us; speedup vs baseline: 2.9134x; 1.2897x over previous
//
#include <hip/hip_runtime.h>
#include <hip/hip_bf16.h>

typedef unsigned short u16;
typedef unsigned int u32;
typedef __attribute__((ext_vector_type(8))) short short8;
typedef __attribute__((ext_vector_type(4))) float f32x4;

#define L_SEQ 4096
#define NCH 64
#define NBATCH 4
#define NW 8                    // waves per block = KV splits
#define KVSPAN (L_SEQ / NW)     // 512 j per wave
#define QB 32                   // q-rows per block (shared by all waves)

__device__ inline u16 f2bf(float f) {
    union { float f; u32 u; } v; v.f = f;
    u32 r = v.u + 0x7fffu + ((v.u >> 16) & 1u);   // round-to-nearest-even
    return (u16)(r >> 16);
}

// ---------------- Kernel 1: QKV projection (3x 64x64 channel GEMM) ----------------
// Qt[n][i][c] (bf16, row-major — only read once per wave).
// Kp: fragment-order keys. For lane = hig*16 + p reading j = jb*16+p, c = half*32+hig*8+e:
//   offset(j,c) = jb*1024 + (c/32)*512 + ((c%32)/8)*128 + (j%16)*8 + c%8
// Vp: fragment-order values. For lane = hig*16 + lo reading c = ct*16+lo, j = j64*64+half*32+hig*8+e:
//   offset(c,j) = (j/64)*4096 + (c/16)*1024 + ((j%64)/32)*512 + ((j%32)/8)*128 + (c%16)*8 + j%8
// Every attention hot-loop load is then base + lane*16B: one coalesced 1KB instruction.
__global__ __launch_bounds__(256) void qkv_kernel(
    const float* __restrict__ x,
    const float* __restrict__ wb, const float* __restrict__ bb,
    const float* __restrict__ wc, const float* __restrict__ bc,
    const float* __restrict__ wd, const float* __restrict__ bd,
    u16* __restrict__ Qt, u16* __restrict__ Kp, u16* __restrict__ Vp)
{
    __shared__ float xs[64][64];       // x tile: [c][px]
    __shared__ float wl[3][64][65];    // padded weights: [mat][o][c]

    const int nb  = blockIdx.y;
    const int i0  = blockIdx.x * 64;
    const int tid = threadIdx.x;

    const float* xbase = x + (size_t)nb * NCH * L_SEQ + i0;
    #pragma unroll
    for (int rep = 0; rep < 16; ++rep) {
        int idx = rep * 256 + tid;
        int c = idx >> 6, px = idx & 63;
        xs[c][px] = xbase[(size_t)c * L_SEQ + px];
    }
    const float* wsrc[3] = { wb, wc, wd };
    for (int m = 0; m < 3; ++m) {
        #pragma unroll
        for (int rep = 0; rep < 16; ++rep) {
            int idx = rep * 256 + tid;
            wl[m][idx >> 6][idx & 63] = wsrc[m][idx];
        }
    }
    __syncthreads();

    const int co  = tid & 63;     // output channel
    const int pg  = tid >> 6;     // pixel group 0..3
    const int px0 = pg * 16;

    float accB[16], accC[16], accD[16];
    const float biasB = bb[co], biasC = bc[co], biasD = bd[co];
    #pragma unroll
    for (int p = 0; p < 16; ++p) { accB[p] = biasB; accC[p] = biasC; accD[p] = biasD; }

    for (int c = 0; c < 64; ++c) {
        const float wbv = wl[0][co][c];
        const float wcv = wl[1][co][c];
        const float wdv = wl[2][co][c];
        #pragma unroll
        for (int p = 0; p < 16; ++p) {
            const float xv = xs[c][px0 + p];
            accB[p] += wbv * xv;
            accC[p] += wcv * xv;
            accD[p] += wdv * xv;
        }
    }

    const size_t nbase = (size_t)nb * L_SEQ * NCH;
    // K fragment-order: co fixed -> half, hig, e fixed; p varies
    const int kbase = (i0 / 16 + pg) * 1024 + (co >> 5) * 512 + ((co & 31) >> 3) * 128 + (co & 7);
    // V fragment-order: co fixed -> ct, lo fixed; j_local = pg*16+p varies
    const int vbase = (i0 >> 6) * 4096 + (co >> 4) * 1024 + (co & 15) * 8;

    #pragma unroll
    for (int p = 0; p < 16; ++p) {
        const int i  = i0 + px0 + p;
        const int jl = px0 + p;   // 0..63
        Kp[nbase + kbase + p * 8] = f2bf(accB[p]);                              // keys    = xb
        Qt[((size_t)(nb * L_SEQ + i)) * NCH + co] = f2bf(accC[p]);              // queries = xc
        Vp[nbase + vbase + (jl >> 5) * 512 + ((jl & 31) >> 3) * 128 + (jl & 7)] // values  = xd
            = f2bf(accD[p]);
    }
}

// ---------------- Kernel 2: flash attention, split-KV, 32 q-rows, coalesced frags ----
// Block = 8 waves sharing one 32-row q-tile. Wave w covers j in [w*512, (w+1)*512).
// R4 structure (known-good 74us); K/V loads now hit the fragment-order layouts:
// every hot-loop global load is base + lane*16B (coalesced 1KB), no gathers.
__global__ __launch_bounds__(512, 4) void attn_kernel(
    const u16* __restrict__ Qt, const u16* __restrict__ Kp,
    const u16* __restrict__ Vp, const float* __restrict__ x,
    const float* __restrict__ alphap, float* __restrict__ out)
{
    // Per-wave region: 32*65 floats (8320 B). During the KV loop the first
    // 4608 B are the wave-private P-transpose buffer (u16[32][72]); after the
    // loop the region holds the fp32 partial O[32][65] (padded).
    __shared__ float smem[NW][QB * 65];
    __shared__ float mlbuf[NW][QB][2];

    const int nb   = blockIdx.y;
    const int i0   = blockIdx.x * QB;
    const int tid  = threadIdx.x;
    const int w    = tid >> 6;
    const int lane = tid & 63;
    const int lo   = lane & 15;
    const int hi   = lane >> 4;

    u16* pbuf = (u16*)(&smem[w][0]);   // [32][72] u16, stride 144 B

    // Q fragments: A[row=lo][k=c], qt selects 16-row half of the 32-row q-tile
    short8 qf[2][2];
    #pragma unroll
    for (int qt = 0; qt < 2; ++qt) {
        const u16* qrow = Qt + ((size_t)(nb * L_SEQ + i0 + qt * 16 + lo)) * NCH + hi * 8;
        qf[qt][0] = *(const short8*)(qrow);
        qf[qt][1] = *(const short8*)(qrow + 32);
    }

    const f32x4 zero = { 0.f, 0.f, 0.f, 0.f };
    f32x4 acc_o[2][4];                 // [qt][ct]; rows q=qt*16+hi*4+r, col c=ct*16+lo
    #pragma unroll
    for (int qt = 0; qt < 2; ++qt)
        #pragma unroll
        for (int ct = 0; ct < 4; ++ct) acc_o[qt][ct] = zero;
    float m_[2][4], l_[2][4];
    #pragma unroll
    for (int qt = 0; qt < 2; ++qt)
        #pragma unroll
        for (int r = 0; r < 4; ++r) { m_[qt][r] = -3.0e38f; l_[qt][r] = 0.f; }

    const u16* KpB = Kp + (size_t)nb * L_SEQ * NCH;
    const u16* VpB = Vp + (size_t)nb * NCH * L_SEQ;

    #pragma unroll 1
    for (int t = 0; t < KVSPAN / 64; ++t) {
        const int j0 = w * KVSPAN + t * 64;

        // ---- S = Q K^T (32 x 64); coalesced fragment loads, shared across q-halves ----
        f32x4 s[2][4];
        #pragma unroll
        for (int jt = 0; jt < 4; ++jt) {
            const u16* kb = KpB + (size_t)(j0 / 16 + jt) * 1024 + lane * 8;
            short8 k0 = *(const short8*)(kb);
            short8 k1 = *(const short8*)(kb + 512);
            #pragma unroll
            for (int qt = 0; qt < 2; ++qt) {
                f32x4 a = zero;
                a = __builtin_amdgcn_mfma_f32_16x16x32_bf16(qf[qt][0], k0, a, 0, 0, 0);
                a = __builtin_amdgcn_mfma_f32_16x16x32_bf16(qf[qt][1], k1, a, 0, 0, 0);
                s[qt][jt] = a;
            }
        }

        // ---- online softmax; row q = qt*16+hi*4+r, col j = jt*16+lo ----
        float scl[2][4];
        #pragma unroll
        for (int qt = 0; qt < 2; ++qt) {
            #pragma unroll
            for (int r = 0; r < 4; ++r) {
                float rm = fmaxf(fmaxf(s[qt][0][r], s[qt][1][r]),
                                 fmaxf(s[qt][2][r], s[qt][3][r]));
                #pragma unroll
                for (int msk = 1; msk < 16; msk <<= 1)
                    rm = fmaxf(rm, __shfl_xor(rm, msk, 64));
                const float mn = fmaxf(m_[qt][r], rm);
                scl[qt][r] = __expf(m_[qt][r] - mn);
                float rs = 0.f;
                float pv[4];
                #pragma unroll
                for (int jt = 0; jt < 4; ++jt) {
                    pv[jt] = __expf(s[qt][jt][r] - mn);
                    rs += pv[jt];
                }
                #pragma unroll
                for (int msk = 1; msk < 16; msk <<= 1)
                    rs += __shfl_xor(rs, msk, 64);
                l_[qt][r] = l_[qt][r] * scl[qt][r] + rs;
                m_[qt][r] = mn;
                // ---- P -> per-wave LDS (transpose to A-fragment layout) ----
                #pragma unroll
                for (int jt = 0; jt < 4; ++jt)
                    pbuf[(qt * 16 + hi * 4 + r) * 72 + jt * 16 + lo] = f2bf(pv[jt]);
            }
        }

        // wave-private buffer: drain this wave's LDS ops only (in-order DS pipe
        // per wave); no block barrier. sched_barrier per rule 18.
        asm volatile("s_waitcnt lgkmcnt(0)" ::: "memory");
        __builtin_amdgcn_sched_barrier(0);

        short8 pf[2][2];
        #pragma unroll
        for (int qt = 0; qt < 2; ++qt) {
            pf[qt][0] = *(const short8*)&pbuf[(qt * 16 + lo) * 72 + hi * 8];
            pf[qt][1] = *(const short8*)&pbuf[(qt * 16 + lo) * 72 + 32 + hi * 8];
        }

        // ---- rescale O ----
        #pragma unroll
        for (int qt = 0; qt < 2; ++qt)
            #pragma unroll
            for (int ct = 0; ct < 4; ++ct)
                #pragma unroll
                for (int r = 0; r < 4; ++r)
                    acc_o[qt][ct][r] *= scl[qt][r];

        // ---- O += P V^T; coalesced fragment loads, shared across q-halves ----
        #pragma unroll
        for (int ct = 0; ct < 4; ++ct) {
            const u16* vb = VpB + (size_t)(j0 >> 6) * 4096 + ct * 1024 + lane * 8;
            short8 v0 = *(const short8*)(vb);
            short8 v1 = *(const short8*)(vb + 512);
            #pragma unroll
            for (int qt = 0; qt < 2; ++qt) {
                acc_o[qt][ct] = __builtin_amdgcn_mfma_f32_16x16x32_bf16(pf[qt][0], v0, acc_o[qt][ct], 0, 0, 0);
                acc_o[qt][ct] = __builtin_amdgcn_mfma_f32_16x16x32_bf16(pf[qt][1], v1, acc_o[qt][ct], 0, 0, 0);
            }
        }
    }

    // ---- write per-wave partial state to LDS ----
    #pragma unroll
    for (int qt = 0; qt < 2; ++qt)
        #pragma unroll
        for (int ct = 0; ct < 4; ++ct)
            #pragma unroll
            for (int r = 0; r < 4; ++r)
                smem[w][(qt * 16 + hi * 4 + r) * 65 + ct * 16 + lo] = acc_o[qt][ct][r];
    if (lo == 0) {
        #pragma unroll
        for (int qt = 0; qt < 2; ++qt)
            #pragma unroll
            for (int r = 0; r < 4; ++r) {
                mlbuf[w][qt * 16 + hi * 4 + r][0] = m_[qt][r];
                mlbuf[w][qt * 16 + hi * 4 + r][1] = l_[qt][r];
            }
    }
    __syncthreads();

    // ---- combine 8 partials + epilogue ----
    // thread -> (q = tid&31, c0 = (tid>>5)*4): covers 32 q x 64 c
    const int q  = tid & 31;
    const int c0 = (tid >> 5) * 4;

    float gm = -3.0e38f;
    #pragma unroll
    for (int s2 = 0; s2 < NW; ++s2) gm = fmaxf(gm, mlbuf[s2][q][0]);

    float Ls = 0.f, O[4] = { 0.f, 0.f, 0.f, 0.f };
    #pragma unroll
    for (int s2 = 0; s2 < NW; ++s2) {
        const float cf = __expf(mlbuf[s2][q][0] - gm);
        Ls += mlbuf[s2][q][1] * cf;
        #pragma unroll
        for (int k = 0; k < 4; ++k)
            O[k] += smem[s2][q * 65 + c0 + k] * cf;
    }
    const float rl    = __builtin_amdgcn_rcpf(Ls);
    const float alpha = alphap[0];

    #pragma unroll
    for (int k = 0; k < 4; ++k) {
        const size_t idx = ((size_t)(nb * NCH + c0 + k)) * L_SEQ + i0 + q;
        out[idx] = alpha * O[k] * rl + x[idx];
    }
}

extern "C" void kernel_launch(void* const* d_in, const int* in_sizes, int n_in,
                              void* d_out, int out_size, void* d_ws, size_t ws_size,
                              hipStream_t stream) {
    const float* x     = (const float*)d_in[0];
    const float* wb    = (const float*)d_in[1];
    const float* bb    = (const float*)d_in[2];
    const float* wc    = (const float*)d_in[3];
    const float* bc    = (const float*)d_in[4];
    const float* wd    = (const float*)d_in[5];
    const float* bd    = (const float*)d_in[6];
    const float* alpha = (const float*)d_in[7];

    const size_t elems = (size_t)NBATCH * L_SEQ * NCH;  // 1,048,576
    u16* Qt = (u16*)d_ws;
    u16* Kp = Qt + elems;
    u16* Vp = Kp + elems;

    qkv_kernel<<<dim3(L_SEQ / 64, NBATCH), 256, 0, stream>>>(
        x, wb, bb, wc, bc, wd, bd, Qt, Kp, Vp);
    attn_kernel<<<dim3(L_SEQ / QB, NBATCH), 512, 0, stream>>>(
        Qt, Kp, Vp, x, alpha, (float*)d_out);
}

// Round 7
// 48.590 us; speedup vs baseline: 3.8944x; 1.3367x over previous
//
#include <hip/hip_runtime.h>
#include <hip/hip_bf16.h>

typedef unsigned short u16;
typedef unsigned int u32;
typedef __attribute__((ext_vector_type(8))) short short8;
typedef __attribute__((ext_vector_type(4))) float f32x4;

#define L_SEQ 4096
#define NCH 64
#define NBATCH 4
#define NW 8                    // waves per block = KV splits
#define KVSPAN (L_SEQ / NW)     // 512 j per wave
#define QB 32                   // q-rows per block (shared by all waves)

__device__ inline u16 f2bf(float f) {
    union { float f; u32 u; } v; v.f = f;
    u32 r = v.u + 0x7fffu + ((v.u >> 16) & 1u);   // round-to-nearest-even
    return (u16)(r >> 16);
}

// hardware packed f32->bf16 (RNE); low16 = a, high16 = b
__device__ inline u32 cvtpk(float a, float b) {
    u32 r;
    asm("v_cvt_pk_bf16_f32 %0, %1, %2" : "=v"(r) : "v"(a), "v"(b));
    return r;
}

// ---------------- Kernel 1: QKV projection (3x 64x64 channel GEMM) ----------------
// Qt[n][i][c] (bf16, row-major).
// Kp: fragment-order keys (A/B-operand lane map, identical for 16x16x32):
//   element offset(j,c) = (j/16)*1024 + (c/32)*512 + ((c%32)/8)*128 + (j%16)*8 + c%8
//   -> attn loads K[j=jb*16+lo][c=hi*8+e] at base + lane*8 elems (coalesced 1KB).
// Vp: sigma-permuted fragment-order values for the swapped PV contraction.
//   Contraction slot k=8*hi+e of each 32-wide mfma maps to physical
//   jj = sigma(hi,e) = (e<4 ? 4*hi+e : 16+4*hi+(e-4)); lane needs
//   V[c=ct*16+lo][j0 + half*32 + sigma(hi,e)] contiguous:
//   element offset(c,j) = (j/64)*4096 + (c/16)*1024 + ((j%64)/32)*512 + lane*8 + e.
__global__ __launch_bounds__(256) void qkv_kernel(
    const float* __restrict__ x,
    const float* __restrict__ wb, const float* __restrict__ bb,
    const float* __restrict__ wc, const float* __restrict__ bc,
    const float* __restrict__ wd, const float* __restrict__ bd,
    u16* __restrict__ Qt, u16* __restrict__ Kp, u16* __restrict__ Vp)
{
    __shared__ float xs[64][64];       // x tile: [c][px]
    __shared__ float wl[3][64][65];    // padded weights: [mat][o][c]

    const int nb  = blockIdx.y;
    const int i0  = blockIdx.x * 64;
    const int tid = threadIdx.x;

    const float* xbase = x + (size_t)nb * NCH * L_SEQ + i0;
    #pragma unroll
    for (int rep = 0; rep < 16; ++rep) {
        int idx = rep * 256 + tid;
        int c = idx >> 6, px = idx & 63;
        xs[c][px] = xbase[(size_t)c * L_SEQ + px];
    }
    const float* wsrc[3] = { wb, wc, wd };
    for (int m = 0; m < 3; ++m) {
        #pragma unroll
        for (int rep = 0; rep < 16; ++rep) {
            int idx = rep * 256 + tid;
            wl[m][idx >> 6][idx & 63] = wsrc[m][idx];
        }
    }
    __syncthreads();

    const int co  = tid & 63;     // output channel
    const int pg  = tid >> 6;     // pixel group 0..3
    const int px0 = pg * 16;

    float accB[16], accC[16], accD[16];
    const float biasB = bb[co], biasC = bc[co], biasD = bd[co];
    #pragma unroll
    for (int p = 0; p < 16; ++p) { accB[p] = biasB; accC[p] = biasC; accD[p] = biasD; }

    for (int c = 0; c < 64; ++c) {
        const float wbv = wl[0][co][c];
        const float wcv = wl[1][co][c];
        const float wdv = wl[2][co][c];
        #pragma unroll
        for (int p = 0; p < 16; ++p) {
            const float xv = xs[c][px0 + p];
            accB[p] += wbv * xv;
            accC[p] += wcv * xv;
            accD[p] += wdv * xv;
        }
    }

    const size_t nbase = (size_t)nb * L_SEQ * NCH;
    // K fragment-order: co fixed -> half, hig, e fixed; p (=j%16) varies
    const int kbase = (i0 / 16 + pg) * 1024 + (co >> 5) * 512 + ((co & 31) >> 3) * 128 + (co & 7);
    // V sigma-order: jl = pg*16+p; half = pg>>1; hi = p>>2; e = (pg&1)*4 + (p&3)
    const int vbase = (i0 >> 6) * 4096 + (co >> 4) * 1024 + (pg >> 1) * 512
                    + (co & 15) * 8 + (pg & 1) * 4;

    #pragma unroll
    for (int p = 0; p < 16; ++p) {
        const int i = i0 + px0 + p;
        Kp[nbase + kbase + p * 8] = f2bf(accB[p]);                     // keys    = xb
        Qt[((size_t)(nb * L_SEQ + i)) * NCH + co] = f2bf(accC[p]);     // queries = xc
        Vp[nbase + vbase + (p >> 2) * 128 + (p & 3)] = f2bf(accD[p]);  // values  = xd
    }
}

// ---------------- Kernel 2: flash attention, split-KV, swapped QK^T, no-LDS loop ----
// Block = 8 waves sharing one 32-row q-tile. Wave w covers j in [w*512, (w+1)*512).
// S^T = mfma(K, Q): lane holds S[i = qt*16+lo][16 j's] -> softmax in-register
// (15-op tree + 2 shfl per row). P packed lane-locally via v_cvt_pk_bf16_f32 in the
// sigma contraction order; V loads hit the sigma-permuted fragment layout at
// base + lane*16B. Zero LDS / zero barriers in the hot loop.
__global__ __launch_bounds__(512, 4) void attn_kernel(
    const u16* __restrict__ Qt, const u16* __restrict__ Kp,
    const u16* __restrict__ Vp, const float* __restrict__ x,
    const float* __restrict__ alphap, float* __restrict__ out)
{
    __shared__ float smem[NW][QB * 65];   // per-wave partial O [q][c], pad 65
    __shared__ float mlbuf[NW][QB][2];

    const int nb   = blockIdx.y;
    const int i0   = blockIdx.x * QB;
    const int tid  = threadIdx.x;
    const int w    = tid >> 6;
    const int lane = tid & 63;
    const int lo   = lane & 15;
    const int hi   = lane >> 4;

    // Q fragments (B operand): col=i=qt*16+lo, k=c=hi*8+e
    short8 qf[2][2];
    #pragma unroll
    for (int qt = 0; qt < 2; ++qt) {
        const u16* qrow = Qt + ((size_t)(nb * L_SEQ + i0 + qt * 16 + lo)) * NCH + hi * 8;
        qf[qt][0] = *(const short8*)(qrow);
        qf[qt][1] = *(const short8*)(qrow + 32);
    }

    const f32x4 zero = { 0.f, 0.f, 0.f, 0.f };
    f32x4 acc_o[2][4];   // [qt][ct]: O^T[c=ct*16+4hi+r][i=qt*16+lo]
    #pragma unroll
    for (int qt = 0; qt < 2; ++qt)
        #pragma unroll
        for (int ct = 0; ct < 4; ++ct) acc_o[qt][ct] = zero;
    float m_[2] = { -3.0e38f, -3.0e38f }, l_[2] = { 0.f, 0.f };

    const u16* KpB = Kp + (size_t)nb * L_SEQ * NCH;
    const u16* VpB = Vp + (size_t)nb * NCH * L_SEQ;

    union PF { u32 u[4]; short8 s; };

    #pragma unroll 1
    for (int t = 0; t < KVSPAN / 64; ++t) {
        const int j0 = w * KVSPAN + t * 64;

        // ---- S^T = K Q^T: s[qt][jt][r] = S[i=qt*16+lo][j0 + jt*16 + 4hi + r] ----
        f32x4 s[2][4];
        #pragma unroll
        for (int jt = 0; jt < 4; ++jt) {
            const u16* kb = KpB + (size_t)(j0 / 16 + jt) * 1024 + lane * 8;
            short8 k0 = *(const short8*)(kb);
            short8 k1 = *(const short8*)(kb + 512);
            #pragma unroll
            for (int qt = 0; qt < 2; ++qt) {
                f32x4 a = zero;
                a = __builtin_amdgcn_mfma_f32_16x16x32_bf16(k0, qf[qt][0], a, 0, 0, 0);
                a = __builtin_amdgcn_mfma_f32_16x16x32_bf16(k1, qf[qt][1], a, 0, 0, 0);
                s[qt][jt] = a;
            }
        }

        // ---- online softmax, in-register per q-row + 2 shfl (lanes lo+16k share i) ----
        float scl[2];
        PF pf[2][2];
        #pragma unroll
        for (int qt = 0; qt < 2; ++qt) {
            float rm = fmaxf(
                fmaxf(fmaxf(fmaxf(s[qt][0][0], s[qt][0][1]), fmaxf(s[qt][0][2], s[qt][0][3])),
                      fmaxf(fmaxf(s[qt][1][0], s[qt][1][1]), fmaxf(s[qt][1][2], s[qt][1][3]))),
                fmaxf(fmaxf(fmaxf(s[qt][2][0], s[qt][2][1]), fmaxf(s[qt][2][2], s[qt][2][3])),
                      fmaxf(fmaxf(s[qt][3][0], s[qt][3][1]), fmaxf(s[qt][3][2], s[qt][3][3]))));
            rm = fmaxf(rm, __shfl_xor(rm, 16, 64));
            rm = fmaxf(rm, __shfl_xor(rm, 32, 64));

            const float mn = fmaxf(m_[qt], rm);
            scl[qt] = __expf(m_[qt] - mn);

            float p[4][4];
            float rs = 0.f;
            #pragma unroll
            for (int jt = 0; jt < 4; ++jt)
                #pragma unroll
                for (int r = 0; r < 4; ++r) {
                    p[jt][r] = __expf(s[qt][jt][r] - mn);
                    rs += p[jt][r];
                }
            rs += __shfl_xor(rs, 16, 64);
            rs += __shfl_xor(rs, 32, 64);
            l_[qt] = l_[qt] * scl[qt] + rs;
            m_[qt] = mn;

            // pack P into sigma contraction order (lane-local)
            pf[qt][0].u[0] = cvtpk(p[0][0], p[0][1]);   // e0,e1: jj=4hi+0,1
            pf[qt][0].u[1] = cvtpk(p[0][2], p[0][3]);   // e2,e3: jj=4hi+2,3
            pf[qt][0].u[2] = cvtpk(p[1][0], p[1][1]);   // e4,e5: jj=16+4hi+0,1
            pf[qt][0].u[3] = cvtpk(p[1][2], p[1][3]);   // e6,e7: jj=16+4hi+2,3
            pf[qt][1].u[0] = cvtpk(p[2][0], p[2][1]);   // +32
            pf[qt][1].u[1] = cvtpk(p[2][2], p[2][3]);
            pf[qt][1].u[2] = cvtpk(p[3][0], p[3][1]);
            pf[qt][1].u[3] = cvtpk(p[3][2], p[3][3]);
        }

        // ---- rescale O by scalar scl[qt] ----
        #pragma unroll
        for (int qt = 0; qt < 2; ++qt)
            #pragma unroll
            for (int ct = 0; ct < 4; ++ct)
                #pragma unroll
                for (int r = 0; r < 4; ++r)
                    acc_o[qt][ct][r] *= scl[qt];

        // ---- O^T += V^T P^T; sigma-ordered coalesced V fragment loads ----
        #pragma unroll
        for (int ct = 0; ct < 4; ++ct) {
            const u16* vb = VpB + (size_t)(j0 >> 6) * 4096 + ct * 1024 + lane * 8;
            short8 v0 = *(const short8*)(vb);
            short8 v1 = *(const short8*)(vb + 512);
            #pragma unroll
            for (int qt = 0; qt < 2; ++qt) {
                acc_o[qt][ct] = __builtin_amdgcn_mfma_f32_16x16x32_bf16(v0, pf[qt][0].s, acc_o[qt][ct], 0, 0, 0);
                acc_o[qt][ct] = __builtin_amdgcn_mfma_f32_16x16x32_bf16(v1, pf[qt][1].s, acc_o[qt][ct], 0, 0, 0);
            }
        }
    }

    // ---- write per-wave partial state to LDS: smem[w][q][c] ----
    #pragma unroll
    for (int qt = 0; qt < 2; ++qt)
        #pragma unroll
        for (int ct = 0; ct < 4; ++ct)
            #pragma unroll
            for (int r = 0; r < 4; ++r)
                smem[w][(qt * 16 + lo) * 65 + ct * 16 + hi * 4 + r] = acc_o[qt][ct][r];
    if (hi == 0) {
        #pragma unroll
        for (int qt = 0; qt < 2; ++qt) {
            mlbuf[w][qt * 16 + lo][0] = m_[qt];
            mlbuf[w][qt * 16 + lo][1] = l_[qt];
        }
    }
    __syncthreads();

    // ---- combine 8 partials + epilogue ----
    // thread -> (q = tid&31, c0 = (tid>>5)*4): covers 32 q x 64 c
    const int q  = tid & 31;
    const int c0 = (tid >> 5) * 4;

    float gm = -3.0e38f;
    #pragma unroll
    for (int s2 = 0; s2 < NW; ++s2) gm = fmaxf(gm, mlbuf[s2][q][0]);

    float Ls = 0.f, O[4] = { 0.f, 0.f, 0.f, 0.f };
    #pragma unroll
    for (int s2 = 0; s2 < NW; ++s2) {
        const float cf = __expf(mlbuf[s2][q][0] - gm);
        Ls += mlbuf[s2][q][1] * cf;
        #pragma unroll
        for (int k = 0; k < 4; ++k)
            O[k] += smem[s2][q * 65 + c0 + k] * cf;
    }
    const float rl    = __builtin_amdgcn_rcpf(Ls);
    const float alpha = alphap[0];

    #pragma unroll
    for (int k = 0; k < 4; ++k) {
        const size_t idx = ((size_t)(nb * NCH + c0 + k)) * L_SEQ + i0 + q;
        out[idx] = alpha * O[k] * rl + x[idx];
    }
}

extern "C" void kernel_launch(void* const* d_in, const int* in_sizes, int n_in,
                              void* d_out, int out_size, void* d_ws, size_t ws_size,
                              hipStream_t stream) {
    const float* x     = (const float*)d_in[0];
    const float* wb    = (const float*)d_in[1];
    const float* bb    = (const float*)d_in[2];
    const float* wc    = (const float*)d_in[3];
    const float* bc    = (const float*)d_in[4];
    const float* wd    = (const float*)d_in[5];
    const float* bd    = (const float*)d_in[6];
    const float* alpha = (const float*)d_in[7];

    const size_t elems = (size_t)NBATCH * L_SEQ * NCH;  // 1,048,576
    u16* Qt = (u16*)d_ws;
    u16* Kp = Qt + elems;
    u16* Vp = Kp + elems;

    qkv_kernel<<<dim3(L_SEQ / 64, NBATCH), 256, 0, stream>>>(
        x, wb, bb, wc, bc, wd, bd, Qt, Kp, Vp);
    attn_kernel<<<dim3(L_SEQ / QB, NBATCH), 512, 0, stream>>>(
        Qt, Kp, Vp, x, alpha, (float*)d_out);
}